// Round 10
// baseline (736.230 us; speedup 1.0000x reference)
//
#include <hip/hip_runtime.h>
#include <hip/hip_bf16.h>
#include <hip/hip_cooperative_groups.h>
#include <math.h>

namespace cg = cooperative_groups;

// Problem constants
#define T_LEN   4096
#define D_DIM   512
#define H_NUM   8
#define HD_DIM  64
#define W_WIN   32
#define HID_DIM 1536
#define M_ROWS  8192   // B*T
#define QKV_LD  1536   // fused q|kv row stride
#define BK 64

typedef __hip_bfloat16 bf16;
typedef __bf16  bf16x8 __attribute__((ext_vector_type(8)));
typedef float   f32x4  __attribute__((ext_vector_type(4)));

__device__ __forceinline__ float b2f(bf16 x) { return __bfloat162float(x); }
__device__ __forceinline__ bf16  f2b(float x){ return __float2bfloat16(x); }

__device__ __forceinline__ float rdP(const void* p, int i, bool f32) {
  return f32 ? ((const float*)p)[i] : b2f(((const bf16*)p)[i]);
}

__device__ __forceinline__ float wave_reduce_sum(float v) {
  #pragma unroll
  for (int off = 32; off; off >>= 1) v += __shfl_xor(v, off, 64);
  return v;
}

// Wave-parallel dtype detection over a fixed 256 dwords of x (deterministic).
__device__ __forceinline__ bool detect_f32(const unsigned* __restrict__ x) {
  int lane = threadIdx.x & 63;
  int votes = 0;
  #pragma unroll
  for (int i = 0; i < 4; ++i) {
    unsigned e = (x[lane * 4 + i] >> 7) & 0xffu;
    votes += (e >= 90u && e <= 140u) ? 1 : 0;
  }
  float v = wave_reduce_sum((float)votes);
  return v < 200.f;
}

// Async global->LDS, 16B per lane; HW writes lds + lane*16 (wave-uniform base).
__device__ __forceinline__ void gload_lds16(const bf16* g, bf16* l) {
  __builtin_amdgcn_global_load_lds(
      (const __attribute__((address_space(1))) unsigned int*)g,
      (__attribute__((address_space(3))) unsigned int*)l, 16, 0, 0);
}

struct Params {
  const void *x, *pre_g, *pre_b, *wq, *wkv, *wo, *attn_g, *attn_b,
             *freqs, *phases, *amp, *w_gate, *w_val, *w_proj, *ffn_g, *ffn_b;
  void* out;
  bf16 *Btqkv, *Bto, *Btg, *Btv, *Btp, *h, *qkvb;
};

// ---------------------------------------------------------------------------
// Shared device helpers (used by BOTH mega kernel and fallback kernels).
// ---------------------------------------------------------------------------
__device__ __forceinline__ void ln_row(
    const void* in, const void* g, const void* bb, void* out, int mode,
    const void* freqs, const void* phases, const void* amp,
    bool f32, bool inF, bool outF, int row)
{
  int lane = threadIdx.x & 63;
  float x[8];
  if (inF) {
    const float* rp = (const float*)in + (size_t)row * D_DIM + lane * 8;
    float4 v0 = *reinterpret_cast<const float4*>(rp);
    float4 v1 = *reinterpret_cast<const float4*>(rp + 4);
    x[0]=v0.x; x[1]=v0.y; x[2]=v0.z; x[3]=v0.w;
    x[4]=v1.x; x[5]=v1.y; x[6]=v1.z; x[7]=v1.w;
  } else {
    bf16x8 v = *reinterpret_cast<const bf16x8*>(
        (const bf16*)in + (size_t)row * D_DIM + lane * 8);
    #pragma unroll
    for (int i = 0; i < 8; ++i) x[i] = (float)v[i];
  }
  float s = 0.f, s2 = 0.f;
  #pragma unroll
  for (int i = 0; i < 8; ++i) { s += x[i]; s2 += x[i]*x[i]; }
  s  = wave_reduce_sum(s);
  s2 = wave_reduce_sum(s2);
  float mu   = s * (1.f / D_DIM);
  float var  = s2 * (1.f / D_DIM) - mu * mu;
  float rstd = rsqrtf(var + 1e-5f);

  int t = row & (T_LEN - 1);
  float ampf = (mode == 1) ? rdP(amp, 0, f32) : 0.f;

  float o[8];
  #pragma unroll
  for (int i = 0; i < 8; ++i) {
    int d = lane * 8 + i;
    float val = (x[i] - mu) * rstd * rdP(g, d, f32) + rdP(bb, d, f32);
    if (mode == 1) {
      float m = sinf(fmaf((float)t, rdP(freqs, d, f32), rdP(phases, d, f32)));
      val *= (1.f + ampf * m);
    }
    o[i] = val;
  }
  if (outF) {
    float* op = (float*)out + (size_t)row * D_DIM + lane * 8;
    *reinterpret_cast<float4*>(op)     = make_float4(o[0], o[1], o[2], o[3]);
    *reinterpret_cast<float4*>(op + 4) = make_float4(o[4], o[5], o[6], o[7]);
  } else {
    bf16x8 ov;
    #pragma unroll
    for (int i = 0; i < 8; ++i) ov[i] = (__bf16)o[i];
    *reinterpret_cast<bf16x8*>((bf16*)out + (size_t)row * D_DIM + lane * 8) = ov;
  }
}

__device__ __forceinline__ void transpose_unit(const Params& p, bool f32,
                                               int bid, char* smem)
{
  const void* src; bf16* dst; int R, C, lid, tiles_x;
  if      (bid < 256)  { src=p.wq;     dst=p.Btqkv;           R=512;  C=512;  lid=bid;      tiles_x=16; }
  else if (bid < 768)  { src=p.wkv;    dst=p.Btqkv + 512*512; R=512;  C=1024; lid=bid-256;  tiles_x=32; }
  else if (bid < 1024) { src=p.wo;     dst=p.Bto;             R=512;  C=512;  lid=bid-768;  tiles_x=16; }
  else if (bid < 1792) { src=p.w_gate; dst=p.Btg;             R=512;  C=1536; lid=bid-1024; tiles_x=48; }
  else if (bid < 2560) { src=p.w_val;  dst=p.Btv;             R=512;  C=1536; lid=bid-1792; tiles_x=48; }
  else                 { src=p.w_proj; dst=p.Btp;             R=1536; C=512;  lid=bid-2560; tiles_x=16; }

  bf16 (*tile)[33] = (bf16 (*)[33])smem;
  int tx = threadIdx.x & 31;
  int ty = threadIdx.x >> 5;
  int c0 = (lid % tiles_x) * 32;
  int r0 = (lid / tiles_x) * 32;
  __syncthreads();
  #pragma unroll
  for (int j = 0; j < 32; j += 8)
    tile[ty + j][tx] = f2b(rdP(src, (size_t)(r0 + ty + j) * C + c0 + tx, f32));
  __syncthreads();
  #pragma unroll
  for (int j = 0; j < 32; j += 8)
    dst[(size_t)(c0 + ty + j) * R + r0 + tx] = tile[tx][ty + j];
}

// 64x64 LDS-staged GEMM tile (R7/R8-validated). XOR-swizzled 16B chunks.
__device__ __forceinline__ void gemm64_tile(
    const bf16* __restrict__ A, const bf16* __restrict__ Bt,
    bf16* Cout, const bf16* extra, int N, int K, int lda, int mode,
    int mbase, int nbase, char* smem)
{
  bf16* As = (bf16*)smem;
  bf16* Bs = (bf16*)(smem + 8192);
  int lane = threadIdx.x & 63;
  int wid  = threadIdx.x >> 6;
  int quad = lane >> 4, l16 = lane & 15;
  int wm = (wid >> 1) * 32, wn = (wid & 1) * 32;

  int srow   = wid * 16 + (lane >> 3);
  int schunk = (lane & 7) ^ (lane >> 3);
  const bf16* Ag = A  + (size_t)(mbase + srow) * lda + schunk * 8;
  const bf16* Bg = Bt + (size_t)(nbase + srow) * K   + schunk * 8;

  f32x4 acc[2][2] = {};

  for (int kit = K / BK; kit > 0; --kit) {
    __syncthreads();
    #pragma unroll
    for (int it = 0; it < 2; ++it) {
      gload_lds16(Ag + (size_t)(it * 8) * lda, &As[(wid * 16 + it * 8) * BK]);
      gload_lds16(Bg + (size_t)(it * 8) * K,   &Bs[(wid * 16 + it * 8) * BK]);
    }
    Ag += BK; Bg += BK;
    __syncthreads();

    #pragma unroll
    for (int ko = 0; ko < 2; ++ko) {
      bf16x8 a[2], b[2];
      #pragma unroll
      for (int i = 0; i < 2; ++i) {
        int c = (ko * 4 + quad) ^ (l16 & 7);
        a[i] = *reinterpret_cast<const bf16x8*>(&As[(wm + i * 16 + l16) * BK + c * 8]);
        b[i] = *reinterpret_cast<const bf16x8*>(&Bs[(wn + i * 16 + l16) * BK + c * 8]);
      }
      #pragma unroll
      for (int i = 0; i < 2; ++i)
        #pragma unroll
        for (int j = 0; j < 2; ++j)
          acc[i][j] = __builtin_amdgcn_mfma_f32_16x16x32_bf16(a[i], b[j], acc[i][j], 0, 0, 0);
    }
  }

  #pragma unroll
  for (int i = 0; i < 2; ++i)
    #pragma unroll
    for (int j = 0; j < 2; ++j)
      #pragma unroll
      for (int r = 0; r < 4; ++r) {
        int row = mbase + wm + i * 16 + quad * 4 + r;
        int col = nbase + wn + j * 16 + l16;
        size_t idx = (size_t)row * N + col;
        float c = acc[i][j][r];
        if (mode == 1) c += b2f(extra[idx]);
        Cout[idx] = f2b(c);
      }
}

// Fused gate+val 64x64 tile (R7/R8-validated).
__device__ __forceinline__ void gateval_tile(
    const bf16* __restrict__ A, const bf16* __restrict__ Btg,
    const bf16* __restrict__ Btv, bf16* __restrict__ Cout,
    int N, int K, int lda, int mbase, int nbase, char* smem)
{
  bf16* As  = (bf16*)smem;
  bf16* Bgs = (bf16*)(smem + 8192);
  bf16* Bvs = (bf16*)(smem + 16384);
  int lane = threadIdx.x & 63;
  int wid  = threadIdx.x >> 6;
  int quad = lane >> 4, l16 = lane & 15;
  int wm = (wid >> 1) * 32, wn = (wid & 1) * 32;

  int srow   = wid * 16 + (lane >> 3);
  int schunk = (lane & 7) ^ (lane >> 3);
  const bf16* Ag  = A   + (size_t)(mbase + srow) * lda + schunk * 8;
  const bf16* Bgg = Btg + (size_t)(nbase + srow) * K   + schunk * 8;
  const bf16* Bvg = Btv + (size_t)(nbase + srow) * K   + schunk * 8;

  f32x4 accg[2][2] = {};
  f32x4 accv[2][2] = {};

  for (int kit = K / BK; kit > 0; --kit) {
    __syncthreads();
    #pragma unroll
    for (int it = 0; it < 2; ++it) {
      gload_lds16(Ag  + (size_t)(it * 8) * lda, &As [(wid * 16 + it * 8) * BK]);
      gload_lds16(Bgg + (size_t)(it * 8) * K,   &Bgs[(wid * 16 + it * 8) * BK]);
      gload_lds16(Bvg + (size_t)(it * 8) * K,   &Bvs[(wid * 16 + it * 8) * BK]);
    }
    Ag += BK; Bgg += BK; Bvg += BK;
    __syncthreads();

    #pragma unroll
    for (int ko = 0; ko < 2; ++ko) {
      bf16x8 a[2], bg[2], bv[2];
      #pragma unroll
      for (int i = 0; i < 2; ++i) {
        int c = (ko * 4 + quad) ^ (l16 & 7);
        a[i]  = *reinterpret_cast<const bf16x8*>(&As [(wm + i * 16 + l16) * BK + c * 8]);
        bg[i] = *reinterpret_cast<const bf16x8*>(&Bgs[(wn + i * 16 + l16) * BK + c * 8]);
        bv[i] = *reinterpret_cast<const bf16x8*>(&Bvs[(wn + i * 16 + l16) * BK + c * 8]);
      }
      #pragma unroll
      for (int i = 0; i < 2; ++i)
        #pragma unroll
        for (int j = 0; j < 2; ++j) {
          accg[i][j] = __builtin_amdgcn_mfma_f32_16x16x32_bf16(a[i], bg[j], accg[i][j], 0, 0, 0);
          accv[i][j] = __builtin_amdgcn_mfma_f32_16x16x32_bf16(a[i], bv[j], accv[i][j], 0, 0, 0);
        }
    }
  }

  #pragma unroll
  for (int i = 0; i < 2; ++i)
    #pragma unroll
    for (int j = 0; j < 2; ++j)
      #pragma unroll
      for (int r = 0; r < 4; ++r) {
        int row = mbase + wm + i * 16 + quad * 4 + r;
        int col = nbase + wn + j * 16 + l16;
        float g = accg[i][j][r];
        float v = accv[i][j][r];
        Cout[(size_t)row * N + col] = f2b(g / (1.f + expf(-g)) * v);
      }
}

// Attention unit (one wave per (16-token tile, head)); R4-R8-validated layouts.
#define VT_BYTES 9216
#define PL_BYTES 2304
#define ATTN_SET (VT_BYTES + PL_BYTES)
__device__ __forceinline__ int vt_addr(int d, int t) { return d * 144 + t * 2; }

__device__ __forceinline__ void attn_unit(bf16* qkv, int unit, char* wbase)
{
  int lane = threadIdx.x & 63;
  int tile = unit >> 3, head = unit & 7;
  int rowbase = tile * 16;
  int t0 = rowbase & (T_LEN - 1);
  int l16 = lane & 15, quad = lane >> 4;
  char* Vl = wbase;
  bf16* Pl = (bf16*)(wbase + VT_BYTES);

  #pragma unroll
  for (int it = 0; it < 6; ++it) {
    int chunk = it * 64 + lane;
    int t  = chunk >> 3;
    int dc = chunk & 7;
    int row = rowbase - 32 + t;
    if (row < 0) row = 0;             // garbage ok: masked by tau=0
    bf16x8 v = *reinterpret_cast<const bf16x8*>(
        qkv + (size_t)row * QKV_LD + 512 + head * 128 + 64 + dc * 8);
    #pragma unroll
    for (int jj = 0; jj < 8; ++jj)
      *(bf16*)(Vl + vt_addr(dc * 8 + jj, t)) = (bf16)(__bf16)v[jj];
  }
  bf16x8 z = {};
  *reinterpret_cast<bf16x8*>(Vl + vt_addr(lane, 48)) = z;
  *reinterpret_cast<bf16x8*>(Vl + vt_addr(lane, 56)) = z;

  bf16x8 aq0, aq1;
  {
    const bf16* qrow = qkv + (size_t)(rowbase + l16) * QKV_LD + head * HD_DIM + quad * 8;
    aq0 = *reinterpret_cast<const bf16x8*>(qrow);
    aq1 = *reinterpret_cast<const bf16x8*>(qrow + 32);
  }

  f32x4 sacc[3] = {};
  #pragma unroll
  for (int jt = 0; jt < 3; ++jt) {
    int tok = rowbase - 32 + jt * 16 + l16;
    if (tok < 0) tok = 0;             // garbage ok: masked
    const bf16* krow = qkv + (size_t)tok * QKV_LD + 512 + head * 128 + quad * 8;
    bf16x8 b0 = *reinterpret_cast<const bf16x8*>(krow);
    bf16x8 b1 = *reinterpret_cast<const bf16x8*>(krow + 32);
    sacc[jt] = __builtin_amdgcn_mfma_f32_16x16x32_bf16(aq0, b0, sacc[jt], 0, 0, 0);
    sacc[jt] = __builtin_amdgcn_mfma_f32_16x16x32_bf16(aq1, b1, sacc[jt], 0, 0, 0);
  }

  #pragma unroll
  for (int jt = 0; jt < 3; ++jt) {
    int j = jt * 16 + l16;
    #pragma unroll
    for (int r = 0; r < 4; ++r) {
      int i = quad * 4 + r;
      bool valid = (j >= i) && (j <= i + 31) && (t0 - 32 + j >= 0);
      float tau = valid ? 1.f / (1.f + expf(-sacc[jt][r] * 0.125f)) : 0.f;
      Pl[i * 72 + j] = f2b(tau);
    }
  }
  #pragma unroll
  for (int r = 0; r < 4; ++r) Pl[(quad * 4 + r) * 72 + 48 + l16] = f2b(0.f);

  // own-wave LDS writes visible to own-wave reads (lgkmcnt); no barrier needed
  bf16x8 ap0 = *reinterpret_cast<const bf16x8*>((char*)Pl + l16 * 144 + quad * 16);
  bf16x8 ap1 = *reinterpret_cast<const bf16x8*>((char*)Pl + l16 * 144 + 64 + quad * 16);

  f32x4 macc[4] = {};
  #pragma unroll
  for (int nt = 0; nt < 4; ++nt) {
    int d = nt * 16 + l16;
    bf16x8 bv0 = *reinterpret_cast<const bf16x8*>(Vl + vt_addr(d, quad * 8));
    bf16x8 bv1 = *reinterpret_cast<const bf16x8*>(Vl + vt_addr(d, 32 + quad * 8));
    macc[nt] = __builtin_amdgcn_mfma_f32_16x16x32_bf16(ap0, bv0, macc[nt], 0, 0, 0);
    macc[nt] = __builtin_amdgcn_mfma_f32_16x16x32_bf16(ap1, bv1, macc[nt], 0, 0, 0);
  }

  #pragma unroll
  for (int nt = 0; nt < 4; ++nt)
    #pragma unroll
    for (int r = 0; r < 4; ++r)
      qkv[(size_t)(rowbase + quad * 4 + r) * QKV_LD + head * HD_DIM + nt * 16 + l16] =
          f2b(macc[nt][r]);
}

// ---------------------------------------------------------------------------
// PERSISTENT COOPERATIVE MEGA-KERNEL — grid-size-agnostic (grid % 8 == 0).
// ---------------------------------------------------------------------------
__global__ __launch_bounds__(256, 4) void mega_kernel(Params p)
{
  __shared__ alignas(16) char smem[24576];
  cg::grid_group grid = cg::this_grid();
  bool f32 = detect_f32((const unsigned*)p.x);
  int wave = threadIdx.x >> 6;
  int G = (int)gridDim.x;

  // S0: weight transposes (3328) + LN(x)->h (2048)
  for (int u = blockIdx.x; u < 5376; u += G) {
    if (u < 3328) transpose_unit(p, f32, u, smem);
    else          ln_row(p.x, p.pre_g, p.pre_b, p.h, 0, nullptr, nullptr, nullptr,
                         f32, f32, false, (u - 3328) * 4 + wave);
  }
  grid.sync();

  // S1: qkv = h @ [wq|wkv]  (3072 tiles; t->(bx,by) bijective, t&7 = XCD)
  #pragma unroll 1
  for (int t = blockIdx.x; t < 3072; t += G) {
    int sub = t & 7, gg = t >> 3;
    int bx = gg >> 4;                  // 0..23
    int by = (gg & 15) * 8 + sub;      // 0..127
    gemm64_tile(p.h, p.Btqkv, p.qkvb, nullptr, 1536, 512, 512, 0,
                by * 64, bx * 64, smem);
  }
  grid.sync();

  // S2: windowed sigmoid attention (4096 units; 4/block-iter, 2 waves x 2 phases)
  #pragma unroll 1
  for (int b = blockIdx.x; b < 1024; b += G) {
    int u0 = b * 4;
    #pragma unroll 1
    for (int ph = 0; ph < 2; ++ph) {
      bool active = (wave >> 1) == ph;
      int unit = u0 + ph * 2 + (wave & 1);
      char* wbase = smem + (wave & 1) * ATTN_SET;
      __syncthreads();                 // LDS sets free before reuse
      if (active) attn_unit(p.qkvb, unit, wbase);
    }
    __syncthreads();
  }
  grid.sync();

  // S3: s1 = h + msg @ wo  (1024 tiles)
  #pragma unroll 1
  for (int t = blockIdx.x; t < 1024; t += G) {
    int sub = t & 7, gg = t >> 3;
    int bx = gg >> 4;                  // 0..7
    int by = (gg & 15) * 8 + sub;
    gemm64_tile(p.qkvb, p.Bto, p.h, p.h, 512, 512, QKV_LD, 1,
                by * 64, bx * 64, smem);
  }
  grid.sync();

  // S4: y = LN(s1) * (1 + amp*sin(t*freqs+phases))
  #pragma unroll 1
  for (int u = blockIdx.x; u < 2048; u += G)
    ln_row(p.h, p.attn_g, p.attn_b, p.h, 1, p.freqs, p.phases, p.amp,
           f32, false, false, u * 4 + wave);
  grid.sync();

  // S5: act = silu(y@Wg) * (y@Wv)  (3072 tiles)
  #pragma unroll 1
  for (int t = blockIdx.x; t < 3072; t += G) {
    int sub = t & 7, gg = t >> 3;
    int bx = gg >> 4;
    int by = (gg & 15) * 8 + sub;
    gateval_tile(p.h, p.Btg, p.Btv, p.qkvb, 1536, 512, 512,
                 by * 64, bx * 64, smem);
  }
  grid.sync();

  // S6: u = y + act @ w_proj  (1024 tiles)
  #pragma unroll 1
  for (int t = blockIdx.x; t < 1024; t += G) {
    int sub = t & 7, gg = t >> 3;
    int bx = gg >> 4;
    int by = (gg & 15) * 8 + sub;
    gemm64_tile(p.qkvb, p.Btp, p.h, p.h, 512, 1536, QKV_LD, 1,
                by * 64, bx * 64, smem);
  }
  grid.sync();

  // S7: out = LN(u)
  #pragma unroll 1
  for (int u = blockIdx.x; u < 2048; u += G)
    ln_row(p.h, p.ffn_g, p.ffn_b, p.out, 0, nullptr, nullptr, nullptr,
           f32, false, f32, u * 4 + wave);
}

// ---------------------------------------------------------------------------
// FALLBACK KERNELS — exact R8 structure (proven, 289 µs).
// ---------------------------------------------------------------------------
__device__ __forceinline__ void swizzle_xy(int gx, int& bx, int& by) {
  int lid = blockIdx.x;
  int sub = lid & 7;
  int grp = lid >> 3;
  bx = grp % gx;
  by = (grp / gx) * 8 + sub;
}

__global__ __launch_bounds__(256) void fb_transpose_all(Params p) {
  __shared__ alignas(16) char smem[2304];
  bool f32 = detect_f32((const unsigned*)p.x);
  transpose_unit(p, f32, blockIdx.x, smem);
}

__global__ __launch_bounds__(256) void fb_ln(
    const void* in, const void* g, const void* bb, void* out, int mode,
    const void* freqs, const void* phases, const void* amp,
    const unsigned* xdet, int inFollows, int outFollows)
{
  bool f32 = detect_f32(xdet);
  ln_row(in, g, bb, out, mode, freqs, phases, amp,
         f32, f32 && inFollows, f32 && outFollows,
         blockIdx.x * 4 + (threadIdx.x >> 6));
}

__global__ __launch_bounds__(256) void fb_gemm64(
    const bf16* A, const bf16* Bt, bf16* Cout, const bf16* extra,
    int N, int K, int lda, int mode, int gx)
{
  __shared__ alignas(16) char smem[16384];
  int bx, by; swizzle_xy(gx, bx, by);
  gemm64_tile(A, Bt, Cout, extra, N, K, lda, mode, by * 64, bx * 64, smem);
}

__global__ __launch_bounds__(256) void fb_gateval(
    const bf16* A, const bf16* Btg, const bf16* Btv, bf16* Cout,
    int N, int K, int lda, int gx)
{
  __shared__ alignas(16) char smem[24576];
  int bx, by; swizzle_xy(gx, bx, by);
  gateval_tile(A, Btg, Btv, Cout, N, K, lda, by * 64, bx * 64, smem);
}

__global__ __launch_bounds__(256) void fb_attn(bf16* qkv) {
  __shared__ alignas(16) char smem[4 * ATTN_SET];
  int wave = threadIdx.x >> 6;
  attn_unit(qkv, blockIdx.x * 4 + wave, smem + wave * ATTN_SET);
}

// ---------------------------------------------------------------------------
extern "C" void kernel_launch(void* const* d_in, const int* in_sizes, int n_in,
                              void* d_out, int out_size, void* d_ws, size_t ws_size,
                              hipStream_t stream)
{
  char* ws = (char*)d_ws;
  Params p;
  p.x      = d_in[0];  p.pre_g  = d_in[1];  p.pre_b  = d_in[2];
  p.wq     = d_in[3];  p.wkv    = d_in[4];  p.wo     = d_in[5];
  p.attn_g = d_in[6];  p.attn_b = d_in[7];  p.freqs  = d_in[8];
  p.phases = d_in[9];  p.amp    = d_in[10]; p.w_gate = d_in[11];
  p.w_val  = d_in[12]; p.w_proj = d_in[13]; p.ffn_g  = d_in[14];
  p.ffn_b  = d_in[15];
  p.out    = d_out;
  p.Btqkv  = (bf16*)(ws + 512);       // 1536 x 512
  p.Bto    = (bf16*)(ws + 1573376);   //  512 x 512
  p.Btg    = (bf16*)(ws + 2097664);   // 1536 x 512
  p.Btv    = (bf16*)(ws + 3670528);   // 1536 x 512
  p.Btp    = (bf16*)(ws + 5243392);   //  512 x 1536
  p.h      = (bf16*)(ws + 6816256);   // 8192 x 512   (h -> s1 -> y -> u)
  p.qkvb   = (bf16*)(ws + 15204864);  // 8192 x 1536  (q|kv; msg; then act)

  // Try the cooperative mega-kernel with a grid the runtime will accept.
  int maxB = 0;
  hipError_t occ = hipOccupancyMaxActiveBlocksPerMultiprocessor(
      &maxB, (const void*)mega_kernel, 256, 0);
  bool coop_ok = false;
  if (occ == hipSuccess && maxB > 0) {
    int gridb = maxB * 256;
    if (gridb > 1024) gridb = 1024;
    gridb &= ~7;                       // grid % 8 == 0 (XCD swizzle)
    if (gridb >= 64) {
      void* args[] = { &p };
      hipError_t e = hipLaunchCooperativeKernel(
          (const void*)mega_kernel, dim3(gridb), dim3(256), args, 0, stream);
      coop_ok = (e == hipSuccess);
    }
  }
  if (coop_ok) return;

  // Fallback: proven R8 multi-kernel path (identical numerics).
  const unsigned* xdet = (const unsigned*)p.x;
  fb_transpose_all<<<3328, 256, 0, stream>>>(p);
  fb_ln<<<2048, 256, 0, stream>>>(p.x, p.pre_g, p.pre_b, p.h, 0,
                                  nullptr, nullptr, nullptr, xdet, 1, 0);
  fb_gemm64<<<3072, 256, 0, stream>>>(p.h, p.Btqkv, p.qkvb, nullptr,
                                      1536, 512, 512, 0, 24);
  fb_attn<<<1024, 256, 0, stream>>>(p.qkvb);
  fb_gemm64<<<1024, 256, 0, stream>>>(p.qkvb, p.Bto, p.h, p.h,
                                      512, 512, QKV_LD, 1, 8);
  fb_ln<<<2048, 256, 0, stream>>>(p.h, p.attn_g, p.attn_b, p.h, 1,
                                  p.freqs, p.phases, p.amp, xdet, 0, 0);
  fb_gateval<<<3072, 256, 0, stream>>>(p.h, p.Btg, p.Btv, p.qkvb,
                                       1536, 512, 512, 24);
  fb_gemm64<<<1024, 256, 0, stream>>>(p.qkvb, p.Btp, p.h, p.h,
                                      512, 1536, QKV_LD, 1, 8);
  fb_ln<<<2048, 256, 0, stream>>>(p.h, p.ffn_g, p.ffn_b, p.out, 0,
                                  nullptr, nullptr, nullptr, xdet, 0, 1);
}

// Round 11
// 289.102 us; speedup vs baseline: 2.5466x; 2.5466x over previous
//
#include <hip/hip_runtime.h>
#include <hip/hip_bf16.h>
#include <math.h>

// Problem constants
#define T_LEN   4096
#define D_DIM   512
#define H_NUM   8
#define HD_DIM  64
#define W_WIN   32
#define HID_DIM 1536
#define M_ROWS  8192   // B*T
#define QKV_LD  1536   // fused q|kv row stride
#define BK 64

typedef __hip_bfloat16 bf16;
typedef __bf16  bf16x8 __attribute__((ext_vector_type(8)));
typedef float   f32x4  __attribute__((ext_vector_type(4)));

__device__ __forceinline__ float b2f(bf16 x) { return __bfloat162float(x); }
__device__ __forceinline__ bf16  f2b(float x){ return __float2bfloat16(x); }

__device__ __forceinline__ float rdP(const void* p, int i, bool f32) {
  return f32 ? ((const float*)p)[i] : b2f(((const bf16*)p)[i]);
}

__device__ __forceinline__ float wave_reduce_sum(float v) {
  #pragma unroll
  for (int off = 32; off; off >>= 1) v += __shfl_xor(v, off, 64);
  return v;
}

// Wave-parallel dtype detection over a fixed 256 dwords of x (deterministic).
__device__ __forceinline__ bool detect_f32(const unsigned* __restrict__ x) {
  int lane = threadIdx.x & 63;
  int votes = 0;
  #pragma unroll
  for (int i = 0; i < 4; ++i) {
    unsigned e = (x[lane * 4 + i] >> 7) & 0xffu;
    votes += (e >= 90u && e <= 140u) ? 1 : 0;
  }
  float v = wave_reduce_sum((float)votes);
  return v < 200.f;
}

// XCD-aware 1-D block swizzle (R8-validated): lid%8 = XCD; same-by tiles
// land on one XCD so the A row-panel is fetched into exactly one L2.
__device__ __forceinline__ void swizzle_xy(int gx, int& bx, int& by) {
  int lid = blockIdx.x;
  int sub = lid & 7;
  int grp = lid >> 3;
  bx = grp % gx;
  by = (grp / gx) * 8 + sub;
}

// ---------------------------------------------------------------------------
// LayerNorm (R2-validated numerics; self-detecting dtype).
// ---------------------------------------------------------------------------
__global__ __launch_bounds__(256) void ln_kernel(
    const void* __restrict__ in, const void* __restrict__ g, const void* __restrict__ bb,
    void* __restrict__ out, int mode,
    const void* __restrict__ freqs, const void* __restrict__ phases,
    const void* __restrict__ amp,
    const unsigned* __restrict__ xdet, int in_follows, int out_follows)
{
  bool f32  = detect_f32(xdet);
  bool inF  = f32 && (in_follows != 0);
  bool outF = f32 && (out_follows != 0);

  int wave = threadIdx.x >> 6;
  int lane = threadIdx.x & 63;
  int row  = blockIdx.x * 4 + wave;

  float x[8];
  if (inF) {
    const float* rp = (const float*)in + (size_t)row * D_DIM + lane * 8;
    float4 v0 = *reinterpret_cast<const float4*>(rp);
    float4 v1 = *reinterpret_cast<const float4*>(rp + 4);
    x[0]=v0.x; x[1]=v0.y; x[2]=v0.z; x[3]=v0.w;
    x[4]=v1.x; x[5]=v1.y; x[6]=v1.z; x[7]=v1.w;
  } else {
    bf16x8 v = *reinterpret_cast<const bf16x8*>(
        (const bf16*)in + (size_t)row * D_DIM + lane * 8);
    #pragma unroll
    for (int i = 0; i < 8; ++i) x[i] = (float)v[i];
  }

  float s = 0.f, s2 = 0.f;
  #pragma unroll
  for (int i = 0; i < 8; ++i) { s += x[i]; s2 += x[i]*x[i]; }
  s  = wave_reduce_sum(s);
  s2 = wave_reduce_sum(s2);
  float mu   = s * (1.f / D_DIM);
  float var  = s2 * (1.f / D_DIM) - mu * mu;
  float rstd = rsqrtf(var + 1e-5f);

  int t = row & (T_LEN - 1);
  float ampf = (mode == 1) ? rdP(amp, 0, f32) : 0.f;

  float o[8];
  #pragma unroll
  for (int i = 0; i < 8; ++i) {
    int d = lane * 8 + i;
    float val = (x[i] - mu) * rstd * rdP(g, d, f32) + rdP(bb, d, f32);
    if (mode == 1) {
      float m = sinf(fmaf((float)t, rdP(freqs, d, f32), rdP(phases, d, f32)));
      val *= (1.f + ampf * m);
    }
    o[i] = val;
  }

  if (outF) {
    float* op = (float*)out + (size_t)row * D_DIM + lane * 8;
    *reinterpret_cast<float4*>(op)     = make_float4(o[0], o[1], o[2], o[3]);
    *reinterpret_cast<float4*>(op + 4) = make_float4(o[4], o[5], o[6], o[7]);
  } else {
    bf16x8 ov;
    #pragma unroll
    for (int i = 0; i < 8; ++i) ov[i] = (__bf16)o[i];
    *reinterpret_cast<bf16x8*>((bf16*)out + (size_t)row * D_DIM + lane * 8) = ov;
  }
}

// ---------------------------------------------------------------------------
// Fused weight transposes (R6-validated; self-detecting dtype).
// ---------------------------------------------------------------------------
__global__ __launch_bounds__(256) void transpose_all_kernel(
    const void* s0, const void* s1, const void* s2, const void* s3,
    const void* s4, const void* s5,
    bf16* d0, bf16* d1, bf16* d2, bf16* d3, bf16* d4, bf16* d5,
    const unsigned* __restrict__ xdet)
{
  bool f32 = detect_f32(xdet);
  int bid = blockIdx.x;
  const void* src; bf16* dst; int R, C, lid, tiles_x;
  if      (bid < 256)  { src=s0; dst=d0; R=512;  C=512;  lid=bid;      tiles_x=16; }
  else if (bid < 768)  { src=s1; dst=d1; R=512;  C=1024; lid=bid-256;  tiles_x=32; }
  else if (bid < 1024) { src=s2; dst=d2; R=512;  C=512;  lid=bid-768;  tiles_x=16; }
  else if (bid < 1792) { src=s3; dst=d3; R=512;  C=1536; lid=bid-1024; tiles_x=48; }
  else if (bid < 2560) { src=s4; dst=d4; R=512;  C=1536; lid=bid-1792; tiles_x=48; }
  else                 { src=s5; dst=d5; R=1536; C=512;  lid=bid-2560; tiles_x=16; }

  __shared__ bf16 tile[32][33];
  int tx = threadIdx.x & 31;
  int ty = threadIdx.x >> 5;
  int c0 = (lid % tiles_x) * 32;
  int r0 = (lid / tiles_x) * 32;
  #pragma unroll
  for (int j = 0; j < 32; j += 8)
    tile[ty + j][tx] = f2b(rdP(src, (size_t)(r0 + ty + j) * C + c0 + tx, f32));
  __syncthreads();
  #pragma unroll
  for (int j = 0; j < 32; j += 8)
    dst[(size_t)(c0 + ty + j) * R + r0 + tx] = tile[tx][ty + j];
}

// ---------------------------------------------------------------------------
// 64x64-tile GEMM, BK=64, register-prefetch pipelined:
// loads for tile k+1 (plain global loads into VGPRs) are issued right after
// the staging barrier of tile k, so they overlap the MFMA section — their
// waitcnt lands at the next iteration's ds_write, not at a barrier (register
// destinations need no drain for s_barrier, unlike global_load_lds DMA).
// LDS layout (R7/R8-validated XOR swizzle): LDS[row][cl] = global[row][cl^(row%8)].
// mode 0: C. 1: C+extra.
// ---------------------------------------------------------------------------
__global__ __launch_bounds__(256) void gemm64_kernel(
    const bf16* __restrict__ A, const bf16* __restrict__ Bt,
    bf16* Cout, const bf16* extra, int N, int K, int lda, int mode, int gx)
{
  __shared__ alignas(16) bf16 As[64 * BK];   // 8 KB
  __shared__ alignas(16) bf16 Bs[64 * BK];   // 8 KB

  int bx, by; swizzle_xy(gx, bx, by);
  int mbase = by * 64, nbase = bx * 64;
  int lane = threadIdx.x & 63;
  int wid  = threadIdx.x >> 6;
  int quad = lane >> 4, l16 = lane & 15;
  int wm = (wid >> 1) * 32, wn = (wid & 1) * 32;

  // staging map: thread covers rows r0 and r0+8 (both ≡ lane>>3 mod 8)
  int r0 = wid * 16 + (lane >> 3);
  int cl = lane & 7;
  int cg = cl ^ (lane >> 3);
  const bf16* Ag0 = A  + (size_t)(mbase + r0) * lda + cg * 8;
  const bf16* Ag1 = Ag0 + (size_t)8 * lda;
  const bf16* Bg0 = Bt + (size_t)(nbase + r0) * K + cg * 8;
  const bf16* Bg1 = Bg0 + (size_t)8 * K;

  bf16x8 rA0 = *reinterpret_cast<const bf16x8*>(Ag0);
  bf16x8 rA1 = *reinterpret_cast<const bf16x8*>(Ag1);
  bf16x8 rB0 = *reinterpret_cast<const bf16x8*>(Bg0);
  bf16x8 rB1 = *reinterpret_cast<const bf16x8*>(Bg1);

  f32x4 acc[2][2] = {};

  for (int kleft = K / BK; kleft > 0; --kleft) {
    __syncthreads();   // prev iteration's fragment reads done
    *reinterpret_cast<bf16x8*>(&As[r0 * BK + cl * 8])       = rA0;
    *reinterpret_cast<bf16x8*>(&As[(r0 + 8) * BK + cl * 8]) = rA1;
    *reinterpret_cast<bf16x8*>(&Bs[r0 * BK + cl * 8])       = rB0;
    *reinterpret_cast<bf16x8*>(&Bs[(r0 + 8) * BK + cl * 8]) = rB1;
    __syncthreads();   // staging visible

    if (kleft > 1) {   // prefetch next tile; overlaps the MFMA below
      Ag0 += BK; Ag1 += BK; Bg0 += BK; Bg1 += BK;
      rA0 = *reinterpret_cast<const bf16x8*>(Ag0);
      rA1 = *reinterpret_cast<const bf16x8*>(Ag1);
      rB0 = *reinterpret_cast<const bf16x8*>(Bg0);
      rB1 = *reinterpret_cast<const bf16x8*>(Bg1);
    }

    #pragma unroll
    for (int ko = 0; ko < 2; ++ko) {
      bf16x8 a[2], b[2];
      #pragma unroll
      for (int i = 0; i < 2; ++i) {
        int c = (ko * 4 + quad) ^ (l16 & 7);
        a[i] = *reinterpret_cast<const bf16x8*>(&As[(wm + i * 16 + l16) * BK + c * 8]);
        b[i] = *reinterpret_cast<const bf16x8*>(&Bs[(wn + i * 16 + l16) * BK + c * 8]);
      }
      #pragma unroll
      for (int i = 0; i < 2; ++i)
        #pragma unroll
        for (int j = 0; j < 2; ++j)
          acc[i][j] = __builtin_amdgcn_mfma_f32_16x16x32_bf16(a[i], b[j], acc[i][j], 0, 0, 0);
    }
  }

  #pragma unroll
  for (int i = 0; i < 2; ++i)
    #pragma unroll
    for (int j = 0; j < 2; ++j)
      #pragma unroll
      for (int r = 0; r < 4; ++r) {
        int row = mbase + wm + i * 16 + quad * 4 + r;
        int col = nbase + wn + j * 16 + l16;
        size_t idx = (size_t)row * N + col;
        float c = acc[i][j][r];
        if (mode == 1) c += b2f(extra[idx]);
        Cout[idx] = f2b(c);
      }
}

// ---------------------------------------------------------------------------
// Fused gate+val 64x64 GEMM, same register-prefetch pipeline:
// act = silu(A@Wg) * (A@Wv). 24 KB LDS.
// ---------------------------------------------------------------------------
__global__ __launch_bounds__(256) void gateval_kernel(
    const bf16* __restrict__ A, const bf16* __restrict__ Btg,
    const bf16* __restrict__ Btv, bf16* __restrict__ Cout,
    int N, int K, int lda, int gx)
{
  __shared__ alignas(16) bf16 As [64 * BK];  // 8 KB
  __shared__ alignas(16) bf16 Bgs[64 * BK];  // 8 KB
  __shared__ alignas(16) bf16 Bvs[64 * BK];  // 8 KB

  int bx, by; swizzle_xy(gx, bx, by);
  int mbase = by * 64, nbase = bx * 64;
  int lane = threadIdx.x & 63;
  int wid  = threadIdx.x >> 6;
  int quad = lane >> 4, l16 = lane & 15;
  int wm = (wid >> 1) * 32, wn = (wid & 1) * 32;

  int r0 = wid * 16 + (lane >> 3);
  int cl = lane & 7;
  int cg = cl ^ (lane >> 3);
  const bf16* Ag0 = A   + (size_t)(mbase + r0) * lda + cg * 8;
  const bf16* Ag1 = Ag0 + (size_t)8 * lda;
  const bf16* Gg0 = Btg + (size_t)(nbase + r0) * K + cg * 8;
  const bf16* Gg1 = Gg0 + (size_t)8 * K;
  const bf16* Vg0 = Btv + (size_t)(nbase + r0) * K + cg * 8;
  const bf16* Vg1 = Vg0 + (size_t)8 * K;

  bf16x8 rA0 = *reinterpret_cast<const bf16x8*>(Ag0);
  bf16x8 rA1 = *reinterpret_cast<const bf16x8*>(Ag1);
  bf16x8 rG0 = *reinterpret_cast<const bf16x8*>(Gg0);
  bf16x8 rG1 = *reinterpret_cast<const bf16x8*>(Gg1);
  bf16x8 rV0 = *reinterpret_cast<const bf16x8*>(Vg0);
  bf16x8 rV1 = *reinterpret_cast<const bf16x8*>(Vg1);

  f32x4 accg[2][2] = {};
  f32x4 accv[2][2] = {};

  for (int kleft = K / BK; kleft > 0; --kleft) {
    __syncthreads();
    *reinterpret_cast<bf16x8*>(&As [r0 * BK + cl * 8])       = rA0;
    *reinterpret_cast<bf16x8*>(&As [(r0 + 8) * BK + cl * 8]) = rA1;
    *reinterpret_cast<bf16x8*>(&Bgs[r0 * BK + cl * 8])       = rG0;
    *reinterpret_cast<bf16x8*>(&Bgs[(r0 + 8) * BK + cl * 8]) = rG1;
    *reinterpret_cast<bf16x8*>(&Bvs[r0 * BK + cl * 8])       = rV0;
    *reinterpret_cast<bf16x8*>(&Bvs[(r0 + 8) * BK + cl * 8]) = rV1;
    __syncthreads();

    if (kleft > 1) {
      Ag0 += BK; Ag1 += BK; Gg0 += BK; Gg1 += BK; Vg0 += BK; Vg1 += BK;
      rA0 = *reinterpret_cast<const bf16x8*>(Ag0);
      rA1 = *reinterpret_cast<const bf16x8*>(Ag1);
      rG0 = *reinterpret_cast<const bf16x8*>(Gg0);
      rG1 = *reinterpret_cast<const bf16x8*>(Gg1);
      rV0 = *reinterpret_cast<const bf16x8*>(Vg0);
      rV1 = *reinterpret_cast<const bf16x8*>(Vg1);
    }

    #pragma unroll
    for (int ko = 0; ko < 2; ++ko) {
      bf16x8 a[2], bg[2], bv[2];
      #pragma unroll
      for (int i = 0; i < 2; ++i) {
        int c = (ko * 4 + quad) ^ (l16 & 7);
        a[i]  = *reinterpret_cast<const bf16x8*>(&As [(wm + i * 16 + l16) * BK + c * 8]);
        bg[i] = *reinterpret_cast<const bf16x8*>(&Bgs[(wn + i * 16 + l16) * BK + c * 8]);
        bv[i] = *reinterpret_cast<const bf16x8*>(&Bvs[(wn + i * 16 + l16) * BK + c * 8]);
      }
      #pragma unroll
      for (int i = 0; i < 2; ++i)
        #pragma unroll
        for (int j = 0; j < 2; ++j) {
          accg[i][j] = __builtin_amdgcn_mfma_f32_16x16x32_bf16(a[i], bg[j], accg[i][j], 0, 0, 0);
          accv[i][j] = __builtin_amdgcn_mfma_f32_16x16x32_bf16(a[i], bv[j], accv[i][j], 0, 0, 0);
        }
    }
  }

  #pragma unroll
  for (int i = 0; i < 2; ++i)
    #pragma unroll
    for (int j = 0; j < 2; ++j)
      #pragma unroll
      for (int r = 0; r < 4; ++r) {
        int row = mbase + wm + i * 16 + quad * 4 + r;
        int col = nbase + wn + j * 16 + l16;
        float g = accg[i][j][r];
        float v = accv[i][j][r];
        Cout[(size_t)row * N + col] = f2b(g / (1.f + expf(-g)) * v);
      }
}

// ---------------------------------------------------------------------------
// MFMA sliding-window sigmoid attention (R4-R8-validated layouts).
// ---------------------------------------------------------------------------
#define VT_BYTES 9216
#define PL_BYTES 2304
#define ATTN_SET (VT_BYTES + PL_BYTES)
__device__ __forceinline__ int vt_addr(int d, int t) { return d * 144 + t * 2; }

__global__ __launch_bounds__(256) void attn_mfma_kernel(bf16* qkv)
{
  __shared__ alignas(16) char lds_raw[4 * ATTN_SET];
  int lane = threadIdx.x & 63;
  int widx = threadIdx.x >> 6;
  int u    = blockIdx.x * 4 + widx;
  int tile = u >> 3, head = u & 7;
  int rowbase = tile * 16;
  int t0   = rowbase & (T_LEN - 1);
  int l16  = lane & 15, quad = lane >> 4;

  char* wbase = lds_raw + widx * ATTN_SET;
  char* Vl = wbase;
  bf16* Pl = (bf16*)(wbase + VT_BYTES);

  #pragma unroll
  for (int it = 0; it < 6; ++it) {
    int chunk = it * 64 + lane;
    int t  = chunk >> 3;
    int dc = chunk & 7;
    int row = rowbase - 32 + t;
    if (row < 0) row = 0;             // garbage ok: masked by tau=0
    bf16x8 v = *reinterpret_cast<const bf16x8*>(
        qkv + (size_t)row * QKV_LD + 512 + head * 128 + 64 + dc * 8);
    #pragma unroll
    for (int jj = 0; jj < 8; ++jj)
      *(bf16*)(Vl + vt_addr(dc * 8 + jj, t)) = (bf16)(__bf16)v[jj];
  }
  bf16x8 z = {};
  *reinterpret_cast<bf16x8*>(Vl + vt_addr(lane, 48)) = z;
  *reinterpret_cast<bf16x8*>(Vl + vt_addr(lane, 56)) = z;

  bf16x8 aq0, aq1;
  {
    const bf16* qrow = qkv + (size_t)(rowbase + l16) * QKV_LD + head * HD_DIM + quad * 8;
    aq0 = *reinterpret_cast<const bf16x8*>(qrow);
    aq1 = *reinterpret_cast<const bf16x8*>(qrow + 32);
  }

  f32x4 sacc[3] = {};
  #pragma unroll
  for (int jt = 0; jt < 3; ++jt) {
    int tok = rowbase - 32 + jt * 16 + l16;
    if (tok < 0) tok = 0;             // garbage ok: masked
    const bf16* krow = qkv + (size_t)tok * QKV_LD + 512 + head * 128 + quad * 8;
    bf16x8 b0 = *reinterpret_cast<const bf16x8*>(krow);
    bf16x8 b1 = *reinterpret_cast<const bf16x8*>(krow + 32);
    sacc[jt] = __builtin_amdgcn_mfma_f32_16x16x32_bf16(aq0, b0, sacc[jt], 0, 0, 0);
    sacc[jt] = __builtin_amdgcn_mfma_f32_16x16x32_bf16(aq1, b1, sacc[jt], 0, 0, 0);
  }

  #pragma unroll
  for (int jt = 0; jt < 3; ++jt) {
    int j = jt * 16 + l16;
    #pragma unroll
    for (int r = 0; r < 4; ++r) {
      int i = quad * 4 + r;
      bool valid = (j >= i) && (j <= i + 31) && (t0 - 32 + j >= 0);
      float tau = valid ? 1.f / (1.f + expf(-sacc[jt][r] * 0.125f)) : 0.f;
      Pl[i * 72 + j] = f2b(tau);
    }
  }
  #pragma unroll
  for (int r = 0; r < 4; ++r) Pl[(quad * 4 + r) * 72 + 48 + l16] = f2b(0.f);

  __syncthreads();   // uniform; orders LDS writes->reads across the block

  bf16x8 ap0 = *reinterpret_cast<const bf16x8*>((char*)Pl + l16 * 144 + quad * 16);
  bf16x8 ap1 = *reinterpret_cast<const bf16x8*>((char*)Pl + l16 * 144 + 64 + quad * 16);

  f32x4 macc[4] = {};
  #pragma unroll
  for (int nt = 0; nt < 4; ++nt) {
    int d = nt * 16 + l16;
    bf16x8 bv0 = *reinterpret_cast<const bf16x8*>(Vl + vt_addr(d, quad * 8));
    bf16x8 bv1 = *reinterpret_cast<const bf16x8*>(Vl + vt_addr(d, 32 + quad * 8));
    macc[nt] = __builtin_amdgcn_mfma_f32_16x16x32_bf16(ap0, bv0, macc[nt], 0, 0, 0);
    macc[nt] = __builtin_amdgcn_mfma_f32_16x16x32_bf16(ap1, bv1, macc[nt], 0, 0, 0);
  }

  #pragma unroll
  for (int nt = 0; nt < 4; ++nt)
    #pragma unroll
    for (int r = 0; r < 4; ++r)
      qkv[(size_t)(rowbase + quad * 4 + r) * QKV_LD + head * HD_DIM + nt * 16 + l16] =
          f2b(macc[nt][r]);
}

// ---------------------------------------------------------------------------
extern "C" void kernel_launch(void* const* d_in, const int* in_sizes, int n_in,
                              void* d_out, int out_size, void* d_ws, size_t ws_size,
                              hipStream_t stream)
{
  const void* x      = d_in[0];
  const void* pre_g  = d_in[1];
  const void* pre_b  = d_in[2];
  const void* wq     = d_in[3];
  const void* wkv    = d_in[4];
  const void* wo     = d_in[5];
  const void* attn_g = d_in[6];
  const void* attn_b = d_in[7];
  const void* freqs  = d_in[8];
  const void* phases = d_in[9];
  const void* amp    = d_in[10];
  const void* w_gate = d_in[11];
  const void* w_val  = d_in[12];
  const void* w_proj = d_in[13];
  const void* ffn_g  = d_in[14];
  const void* ffn_b  = d_in[15];
  const unsigned* xdet = (const unsigned*)x;

  char* ws = (char*)d_ws;
  bf16* Btqkv = (bf16*)(ws + 512);       // 1536 x 512
  bf16* Bto   = (bf16*)(ws + 1573376);   //  512 x 512
  bf16* Btg   = (bf16*)(ws + 2097664);   // 1536 x 512
  bf16* Btv   = (bf16*)(ws + 3670528);   // 1536 x 512
  bf16* Btp   = (bf16*)(ws + 5243392);   //  512 x 1536
  bf16* h     = (bf16*)(ws + 6816256);   // 8192 x 512   (h -> s1 -> y -> u)
  bf16* qkvb  = (bf16*)(ws + 15204864);  // 8192 x 1536  (q|kv; msg in-place; then act)
  bf16* gb    = qkvb;

  transpose_all_kernel<<<3328, 256, 0, stream>>>(
      wq, wkv, wo, w_gate, w_val, w_proj,
      Btqkv, Btqkv + 512 * 512, Bto, Btg, Btv, Btp, xdet);

  // h = LN(x)
  ln_kernel<<<2048, 256, 0, stream>>>(x, pre_g, pre_b, h, 0,
                                      nullptr, nullptr, nullptr, xdet, 1, 0);

  // qkv = h @ [wq|wkv]  (fused, N=1536)
  gemm64_kernel<<<3072, 256, 0, stream>>>(h, Btqkv, qkvb, nullptr,
                                          1536, 512, 512, 0, 24);

  // msg = window-attention (in-place over q slot)
  attn_mfma_kernel<<<1024, 256, 0, stream>>>(qkvb);

  // s1 = h + msg @ wo
  gemm64_kernel<<<1024, 256, 0, stream>>>(qkvb, Bto, h, h,
                                          512, 512, QKV_LD, 1, 8);

  // y = LN(s1) * (1 + amp*sin(t*freqs+phases))
  ln_kernel<<<2048, 256, 0, stream>>>(h, attn_g, attn_b, h, 1,
                                      freqs, phases, amp, xdet, 0, 0);

  // act = silu(y @ w_gate) * (y @ w_val)
  gateval_kernel<<<3072, 256, 0, stream>>>(h, Btg, Btv, gb,
                                           1536, 512, 512, 24);

  // u = y + act @ w_proj
  gemm64_kernel<<<1024, 256, 0, stream>>>(gb, Btp, h, h,
                                          512, 1536, QKV_LD, 1, 8);

  // out = LN(u)
  ln_kernel<<<2048, 256, 0, stream>>>(h, ffn_g, ffn_b, d_out, 0,
                                      nullptr, nullptr, nullptr, xdet, 0, 1);
}